// Round 5
// baseline (593.355 us; speedup 1.0000x reference)
//
#include <hip/hip_runtime.h>
#include <stdint.h>

#define DEVINL __device__ __forceinline__

typedef unsigned short u16;
typedef __attribute__((ext_vector_type(8))) __bf16 bf16x8;
typedef __attribute__((ext_vector_type(4))) float f32x4;

static constexpr int SEQ    = 2048;
static constexpr int DMODEL = 2048;
static constexpr int NHEAD  = 32;
static constexpr int NGRP   = 8;
static constexpr int DHEAD  = 64;
static constexpr int MTOK   = 2 * SEQ;                       // 4096 tokens (B*S)
static constexpr int NQKV   = NHEAD*DHEAD + 2*NGRP*DHEAD;    // 3072

DEVINL u16 f2bf(float f) {                 // f32 -> bf16 RNE
  unsigned u = __builtin_bit_cast(unsigned, f);
  u += 0x7fffu + ((u >> 16) & 1u);
  return (u16)(u >> 16);
}
DEVINL float bf2f(u16 v) {
  unsigned u = (unsigned)v << 16;
  return __builtin_bit_cast(float, u);
}

DEVINL void gld16(const void* g, void* l) {   // global -> LDS direct, 16B/lane
  typedef __attribute__((address_space(1))) const void* gp_t;
  typedef __attribute__((address_space(3))) void* lp_t;
  __builtin_amdgcn_global_load_lds((gp_t)g, (lp_t)l, 16, 0, 0);
}

DEVINL f32x4 mfma16(bf16x8 a, bf16x8 b, f32x4 c) {
  return __builtin_amdgcn_mfma_f32_16x16x32_bf16(a, b, c, 0, 0, 0);
}

// ---------------- x: f32 -> bf16 (vectorized) ----------------
__global__ void k_cvt(const float* __restrict__ s, u16* __restrict__ d) {
  int i = (blockIdx.x * 256 + threadIdx.x) * 4;
  float4 v = *reinterpret_cast<const float4*>(s + i);
  ushort4 o;
  o.x = f2bf(v.x); o.y = f2bf(v.y); o.z = f2bf(v.z); o.w = f2bf(v.w);
  *reinterpret_cast<ushort4*>(d + i) = o;
}

// ---- weights: transpose + cast. dst[n][k] = src[k][n], dst leading dim = DMODEL ----
__global__ void k_tconv(const float* __restrict__ src, u16* __restrict__ dst, int N) {
  __shared__ float t[32][33];
  int n0 = blockIdx.x * 32, k0 = blockIdx.y * 32;
  int tx = threadIdx.x, ty = threadIdx.y;   // 32 x 8
  #pragma unroll
  for (int r = 0; r < 32; r += 8)
    t[r + ty][tx] = src[(size_t)(k0 + r + ty) * N + n0 + tx];
  __syncthreads();
  #pragma unroll
  for (int r = 0; r < 32; r += 8)
    dst[(size_t)(n0 + r + ty) * DMODEL + k0 + tx] = f2bf(t[tx][r + ty]);
}

__global__ void k_packbias(const float* __restrict__ bq, const float* __restrict__ bk,
                           const float* __restrict__ bv, float* __restrict__ d) {
  int i = blockIdx.x * 256 + threadIdx.x;   // 3072 threads
  d[i] = i < 2048 ? bq[i] : (i < 2560 ? bk[i - 2048] : bv[i - 2560]);
}

// ---- V transpose: vT[((b*8+g)*64 + d)][s] = qkv[(b*2048+s)*NQKV + 2560 + g*64 + d] ----
__global__ void k_vt(const u16* __restrict__ qkv, u16* __restrict__ vT) {
  __shared__ u16 t[64][65];
  const int blk = blockIdx.x;        // b*256 + g*32 + st   (2*8*32 = 512)
  const int st = blk & 31, g = (blk >> 5) & 7, bb = blk >> 8;
  const int s0 = st * 64;
  const int tx = threadIdx.x & 63, ty = threadIdx.x >> 6;  // 64 x 4
  #pragma unroll
  for (int r = 0; r < 64; r += 4)
    t[r + ty][tx] = qkv[((size_t)bb * 2048 + s0 + r + ty) * NQKV + 2560 + g * 64 + tx];
  __syncthreads();
  #pragma unroll
  for (int r = 0; r < 64; r += 4)
    vT[((size_t)((bb * 8 + g) * 64) + r + ty) * SEQ + s0 + tx] = t[tx][r + ty];
}

// ---------------- bf16 GEMM: C[M][ldc] = A[M][K] * Bt[N][K]^T + bias ----------------
// m97-verbatim structure: 128x128 tile, BK=32, 4 waves, global_load_lds(16B),
// LINEAR LDS layout (no swizzle), 2 barriers per K-step.
// F32OUT: store float (final output) vs bf16 (intermediate).
template<int F32OUT>
__global__ __launch_bounds__(256, 3)
void k_gemm(const u16* __restrict__ A, const u16* __restrict__ Bt,
            const float* __restrict__ bias, void* __restrict__ Cv,
            int K, int ldc)
{
  __shared__ __align__(16) u16 lA[128 * 32];
  __shared__ __align__(16) u16 lB[128 * 32];
  const int tid = threadIdx.x;
  const int lane = tid & 63, wid = tid >> 6;
  const int fr = lane & 15, fq = lane >> 4;
  const int n0 = blockIdx.x * 128, m0 = blockIdx.y * 128;
  const int wr = wid >> 1, wc = wid & 1;    // wave's 64x64 output sub-tile

  f32x4 acc[4][4];
  #pragma unroll
  for (int i = 0; i < 4; ++i)
    #pragma unroll
    for (int j = 0; j < 4; ++j) acc[i][j] = f32x4{0.f, 0.f, 0.f, 0.f};

  const int s0 = (wid * 2 + 0) * 64 + lane;
  const int s1 = (wid * 2 + 1) * 64 + lane;
  const int r0 = s0 >> 2, k0s = 8 * (s0 & 3);
  const int r1 = s1 >> 2, k1s = 8 * (s1 & 3);
  const u16* gA0 = A  + (size_t)(m0 + r0) * K + k0s;
  const u16* gA1 = A  + (size_t)(m0 + r1) * K + k1s;
  const u16* gB0 = Bt + (size_t)(n0 + r0) * K + k0s;
  const u16* gB1 = Bt + (size_t)(n0 + r1) * K + k1s;
  u16* lA0 = &lA[(wid * 2 + 0) * 512];
  u16* lA1 = &lA[(wid * 2 + 1) * 512];
  u16* lB0 = &lB[(wid * 2 + 0) * 512];
  u16* lB1 = &lB[(wid * 2 + 1) * 512];

  int aoff[4], boff[4];                     // linear ds_read byte offsets
  #pragma unroll
  for (int i = 0; i < 4; ++i) {
    aoff[i] = (wr * 64 + i * 16 + fr) * 64 + fq * 16;
    boff[i] = (wc * 64 + i * 16 + fr) * 64 + fq * 16;
  }
  const char* laB = (const char*)lA;
  const char* lbB = (const char*)lB;

  for (int kt = 0; kt < K; kt += 32) {
    gld16(gA0, lA0); gld16(gA1, lA1);
    gld16(gB0, lB0); gld16(gB1, lB1);
    gA0 += 32; gA1 += 32; gB0 += 32; gB1 += 32;
    __syncthreads();                         // drains vmcnt -> tiles visible
    bf16x8 a[4], b[4];
    #pragma unroll
    for (int i = 0; i < 4; ++i) a[i] = *(const bf16x8*)(laB + aoff[i]);
    #pragma unroll
    for (int j = 0; j < 4; ++j) b[j] = *(const bf16x8*)(lbB + boff[j]);
    #pragma unroll
    for (int i = 0; i < 4; ++i)
      #pragma unroll
      for (int j = 0; j < 4; ++j)
        acc[i][j] = mfma16(a[i], b[j], acc[i][j]);
    __syncthreads();                         // before next overwrite
  }

  // epilogue: C/D layout col = lane&15, row = (lane>>4)*4 + t  [verified m89/m91]
  #pragma unroll
  for (int i = 0; i < 4; ++i) {
    const int row = m0 + wr * 64 + i * 16 + fq * 4;
    #pragma unroll
    for (int j = 0; j < 4; ++j) {
      const int col = n0 + wc * 64 + j * 16 + fr;
      const float bvl = bias[col];
      #pragma unroll
      for (int t = 0; t < 4; ++t) {
        const float val = acc[i][j][t] + bvl;
        if (F32OUT)
          ((float*)Cv)[(size_t)(row + t) * ldc + col] = val;
        else
          ((u16*)Cv)[(size_t)(row + t) * ldc + col] = f2bf(val);
      }
    }
  }
}

// ---------------- MFMA flash attention, register-pipelined ----------------
// 1 wave = 16 q-rows of one (b,h); KV tile = 64. K/V frags prefetched into
// registers one tile ahead (latency hides under softmax + P-roundtrip).
// P goes through per-wave XOR-swizzled LDS (C-layout -> A-layout). No cross-wave sync.
__global__ __launch_bounds__(256, 3)
void k_attn(const u16* __restrict__ qkv, const u16* __restrict__ vT,
            u16* __restrict__ ctx)
{
  __shared__ __align__(16) u16 pls[4][1024];     // per-wave 16x64 bf16, XOR-swizzled
  const int tid = threadIdx.x, lane = tid & 63, wid = tid >> 6;
  const int fr = lane & 15, fq = lane >> 4;
  const int h = blockIdx.y, bb = blockIdx.z, g = h >> 2;   // GS = 4
  const int q0 = blockIdx.x * 64 + wid * 16;
  const size_t tokbase = (size_t)bb * SEQ;

  bf16x8 aq[2];                                  // Q A-frags (16 rows x 64 d)
  {
    const u16* qp = qkv + (tokbase + q0 + fr) * NQKV + h * 64 + fq * 8;
    aq[0] = *(const bf16x8*)qp;
    aq[1] = *(const bf16x8*)(qp + 32);
  }
  f32x4 ao[4];
  #pragma unroll
  for (int j = 0; j < 4; ++j) ao[j] = f32x4{0.f, 0.f, 0.f, 0.f};
  float mrow[4] = {-3e38f, -3e38f, -3e38f, -3e38f};
  float lrow[4] = {0.f, 0.f, 0.f, 0.f};

  const u16* kbase = qkv + tokbase * NQKV + 2048 + g * 64;
  const u16* vbase = vT + (size_t)(bb * 8 + g) * 64 * SEQ;
  char* myp = (char*)&pls[wid][0];
  const float cs  = 0.18033688011112042f;        // log2(e) / sqrt(64)
  const float thr = 8.0f / cs;                   // defer-max threshold (raw-score units)

  // preload tile-0 K and V fragments
  bf16x8 kf[2][4], vf[2][4];
  #pragma unroll
  for (int ks = 0; ks < 2; ++ks)
    #pragma unroll
    for (int j = 0; j < 4; ++j) {
      kf[ks][j] = *(const bf16x8*)(kbase + (size_t)(j * 16 + fr) * NQKV + ks * 32 + fq * 8);
      vf[ks][j] = *(const bf16x8*)(vbase + (size_t)(j * 16 + fr) * SEQ + ks * 32 + fq * 8);
    }

  for (int tk = 0; tk < SEQ; tk += 64) {
    const int tn = (tk + 64 < SEQ) ? tk + 64 : 0;    // prefetch target (wrap: harmless)

    // S = Q K^T  (raw scores; scale folded into exp2 constant)
    f32x4 as[4];
    #pragma unroll
    for (int j = 0; j < 4; ++j) as[j] = f32x4{0.f, 0.f, 0.f, 0.f};
    __builtin_amdgcn_s_setprio(1);
    #pragma unroll
    for (int ks = 0; ks < 2; ++ks)
      #pragma unroll
      for (int j = 0; j < 4; ++j)
        as[j] = mfma16(aq[ks], kf[ks][j], as[j]);
    __builtin_amdgcn_s_setprio(0);

    // prefetch next K tile (in flight across softmax + P roundtrip)
    #pragma unroll
    for (int ks = 0; ks < 2; ++ks)
      #pragma unroll
      for (int j = 0; j < 4; ++j)
        kf[ks][j] = *(const bf16x8*)(kbase + (size_t)(tn + j * 16 + fr) * NQKV + ks * 32 + fq * 8);

    // online softmax: q-row = fq*4 + t (C-layout rows), key = j*16 + fr
    float mx[4];
    float gmax = -3e38f;
    #pragma unroll
    for (int t = 0; t < 4; ++t) {
      float m2 = fmaxf(fmaxf(as[0][t], as[1][t]), fmaxf(as[2][t], as[3][t]));
      #pragma unroll
      for (int off = 1; off < 16; off <<= 1) m2 = fmaxf(m2, __shfl_xor(m2, off));
      mx[t] = m2;
      gmax = fmaxf(gmax, m2 - mrow[t]);
    }
    if (!__all(gmax <= thr)) {                     // T13 defer-max: rescale only on growth
      #pragma unroll
      for (int t = 0; t < 4; ++t) {
        const float mn = fmaxf(mrow[t], mx[t]);
        const float rs = exp2f((mrow[t] - mn) * cs);
        mrow[t] = mn;
        lrow[t] *= rs;
        #pragma unroll
        for (int j = 0; j < 4; ++j) ao[j][t] *= rs;
      }
    }
    float sum[4] = {0.f, 0.f, 0.f, 0.f};
    #pragma unroll
    for (int j = 0; j < 4; ++j) {
      #pragma unroll
      for (int t = 0; t < 4; ++t) {
        float p = exp2f((as[j][t] - mrow[t]) * cs);
        sum[t] += p;
        int prow = fq * 4 + t, pcol = j * 16 + fr;
        *(u16*)(myp + ((prow * 128 + pcol * 2) ^ ((prow & 7) << 4))) = f2bf(p);
      }
    }
    #pragma unroll
    for (int t = 0; t < 4; ++t) {
      float s = sum[t];
      #pragma unroll
      for (int off = 1; off < 16; off <<= 1) s += __shfl_xor(s, off);
      lrow[t] += s;
    }

    asm volatile("s_waitcnt lgkmcnt(0)" ::: "memory");  // P writes -> P reads (same wave)

    // O += P V : A-frag from LDS (swizzled), B-frag from prefetched regs
    __builtin_amdgcn_s_setprio(1);
    #pragma unroll
    for (int ks = 0; ks < 2; ++ks) {
      bf16x8 pa = *(const bf16x8*)(myp + ((fr * 128 + ks * 64 + fq * 16) ^ ((fr & 7) << 4)));
      #pragma unroll
      for (int j = 0; j < 4; ++j)
        ao[j] = mfma16(pa, vf[ks][j], ao[j]);
    }
    __builtin_amdgcn_s_setprio(0);

    // prefetch next V tile (latency hides under next tile's QK + softmax)
    #pragma unroll
    for (int ks = 0; ks < 2; ++ks)
      #pragma unroll
      for (int j = 0; j < 4; ++j)
        vf[ks][j] = *(const bf16x8*)(vbase + (size_t)(j * 16 + fr) * SEQ + tn + ks * 32 + fq * 8);
  }
  // normalize + store ctx [token][h*64 + d]
  #pragma unroll
  for (int t = 0; t < 4; ++t) {
    const int qrow = q0 + fq * 4 + t;
    const float inv = 1.0f / lrow[t];
    #pragma unroll
    for (int j = 0; j < 4; ++j)
      ctx[(tokbase + qrow) * DMODEL + h * 64 + j * 16 + fr] = f2bf(ao[j][t] * inv);
  }
}

extern "C" void kernel_launch(void* const* d_in, const int* in_sizes, int n_in,
                              void* d_out, int out_size, void* d_ws, size_t ws_size,
                              hipStream_t stream) {
  const float* x  = (const float*)d_in[0];
  const float* Wq = (const float*)d_in[1];
  const float* bq = (const float*)d_in[2];
  const float* Wk = (const float*)d_in[3];
  const float* bk = (const float*)d_in[4];
  const float* Wv = (const float*)d_in[5];
  const float* bv = (const float*)d_in[6];
  const float* Wo = (const float*)d_in[7];
  const float* bo = (const float*)d_in[8];

  char* ws = (char*)d_ws;
  size_t off = 0;
  auto take = [&](size_t bytes) { char* p = ws + off; off += (bytes + 255) & ~(size_t)255; return p; };
  u16*   xb    = (u16*)  take((size_t)MTOK * DMODEL * 2);   // x bf16; REUSED as ctx after gemm1
  u16*   wqkvT = (u16*)  take((size_t)NQKV * DMODEL * 2);   // [Wq;Wk;Wv] transposed
  u16*   woT   = (u16*)  take((size_t)DMODEL * DMODEL * 2); // Wo transposed
  u16*   qkv   = (u16*)  take((size_t)MTOK * NQKV * 2);     // projections (Q,K,V)
  u16*   vTb   = (u16*)  take((size_t)2 * NGRP * DHEAD * SEQ * 2); // V^T [b,g,d,s]
  float* bqkv  = (float*)take((size_t)NQKV * 4);            // packed qkv bias

  // ws overflow guard: if scratch too small, emit zeros (signature: absmax == max|ref|)
  if (off > ws_size) {
    hipMemsetAsync(d_out, 0, (size_t)out_size * 4, stream);
    return;
  }

  dim3 tb(32, 8);
  k_cvt<<<(MTOK * DMODEL) / (4 * 256), 256, 0, stream>>>(x, xb);
  k_tconv<<<dim3(64, 64), tb, 0, stream>>>(Wq, wqkvT, 2048);
  k_tconv<<<dim3(16, 64), tb, 0, stream>>>(Wk, wqkvT + (size_t)2048 * DMODEL, 512);
  k_tconv<<<dim3(16, 64), tb, 0, stream>>>(Wv, wqkvT + (size_t)2560 * DMODEL, 512);
  k_tconv<<<dim3(64, 64), tb, 0, stream>>>(Wo, woT, 2048);
  k_packbias<<<NQKV / 256, 256, 0, stream>>>(bq, bk, bv, bqkv);

  // QKV projection: M=4096, N=3072, K=2048 (bf16 out)
  k_gemm<0><<<dim3(NQKV / 128, MTOK / 128), 256, 0, stream>>>(
      xb, wqkvT, bqkv, qkv, DMODEL, NQKV);

  // V transpose for the PV step's B-operand
  k_vt<<<512, 256, 0, stream>>>(qkv, vTb);

  // MFMA flash attention: grid = (q-tiles, heads, batch); ctx into xb
  u16* ctxb = xb;
  k_attn<<<dim3(SEQ / 64, NHEAD, 2), 256, 0, stream>>>(qkv, vTb, ctxb);

  // output projection: M=4096, N=2048, K=2048 -> d_out (FLOAT32)
  k_gemm<1><<<dim3(DMODEL / 128, MTOK / 128), 256, 0, stream>>>(
      ctxb, woT, bo, d_out, DMODEL, DMODEL);
}

// Round 6
// 370.609 us; speedup vs baseline: 1.6010x; 1.6010x over previous
//
#include <hip/hip_runtime.h>
#include <stdint.h>

#define DEVINL __device__ __forceinline__

typedef unsigned short u16;
typedef unsigned int   u32;
typedef __attribute__((ext_vector_type(8)))  __bf16 bf16x8;
typedef __attribute__((ext_vector_type(4)))  float  f32x4;
typedef __attribute__((ext_vector_type(16))) float  f32x16;
typedef __attribute__((ext_vector_type(4)))  u32    u32x4;

static constexpr int SEQ    = 2048;
static constexpr int DMODEL = 2048;
static constexpr int NHEAD  = 32;
static constexpr int NGRP   = 8;
static constexpr int DHEAD  = 64;
static constexpr int MTOK   = 2 * SEQ;                       // 4096 tokens (B*S)
static constexpr int NQKV   = NHEAD*DHEAD + 2*NGRP*DHEAD;    // 3072

DEVINL u16 f2bf(float f) {                 // f32 -> bf16 RNE
  unsigned u = __builtin_bit_cast(unsigned, f);
  u += 0x7fffu + ((u >> 16) & 1u);
  return (u16)(u >> 16);
}

DEVINL void gld16(const void* g, void* l) {   // global -> LDS direct, 16B/lane
  typedef __attribute__((address_space(1))) const void* gp_t;
  typedef __attribute__((address_space(3))) void* lp_t;
  __builtin_amdgcn_global_load_lds((gp_t)g, (lp_t)l, 16, 0, 0);
}

DEVINL f32x4 mfma16(bf16x8 a, bf16x8 b, f32x4 c) {
  return __builtin_amdgcn_mfma_f32_16x16x32_bf16(a, b, c, 0, 0, 0);
}
DEVINL f32x16 mfma32(bf16x8 a, bf16x8 b, f32x16 c) {
  return __builtin_amdgcn_mfma_f32_32x32x16_bf16(a, b, c, 0, 0, 0);
}
DEVINL u32 cvtpk(float lo, float hi_) {        // bf16(lo) in low16, bf16(hi_) in high16
  u32 r;
  asm("v_cvt_pk_bf16_f32 %0, %1, %2" : "=v"(r) : "v"(lo), "v"(hi_));
  return r;
}

// ---------------- x: f32 -> bf16 (vectorized) ----------------
__global__ void k_cvt(const float* __restrict__ s, u16* __restrict__ d) {
  int i = (blockIdx.x * 256 + threadIdx.x) * 4;
  float4 v = *reinterpret_cast<const float4*>(s + i);
  ushort4 o;
  o.x = f2bf(v.x); o.y = f2bf(v.y); o.z = f2bf(v.z); o.w = f2bf(v.w);
  *reinterpret_cast<ushort4*>(d + i) = o;
}

// ---- weights: transpose + cast. dst[n][k] = src[k][n], dst leading dim = DMODEL ----
__global__ void k_tconv(const float* __restrict__ src, u16* __restrict__ dst, int N) {
  __shared__ float t[32][33];
  int n0 = blockIdx.x * 32, k0 = blockIdx.y * 32;
  int tx = threadIdx.x, ty = threadIdx.y;   // 32 x 8
  #pragma unroll
  for (int r = 0; r < 32; r += 8)
    t[r + ty][tx] = src[(size_t)(k0 + r + ty) * N + n0 + tx];
  __syncthreads();
  #pragma unroll
  for (int r = 0; r < 32; r += 8)
    dst[(size_t)(n0 + r + ty) * DMODEL + k0 + tx] = f2bf(t[tx][r + ty]);
}

__global__ void k_packbias(const float* __restrict__ bq, const float* __restrict__ bk,
                           const float* __restrict__ bv, float* __restrict__ d) {
  int i = blockIdx.x * 256 + threadIdx.x;   // 3072 threads
  d[i] = i < 2048 ? bq[i] : (i < 2560 ? bk[i - 2048] : bv[i - 2560]);
}

// ---- V transpose: vT[((b*8+g)*64 + d)][s] = qkv[(b*2048+s)*NQKV + 2560 + g*64 + d] ----
__global__ void k_vt(const u16* __restrict__ qkv, u16* __restrict__ vT) {
  __shared__ u16 t[64][65];
  const int blk = blockIdx.x;        // b*256 + g*32 + st   (2*8*32 = 512)
  const int st = blk & 31, g = (blk >> 5) & 7, bb = blk >> 8;
  const int s0 = st * 64;
  const int tx = threadIdx.x & 63, ty = threadIdx.x >> 6;  // 64 x 4
  #pragma unroll
  for (int r = 0; r < 64; r += 4)
    t[r + ty][tx] = qkv[((size_t)bb * 2048 + s0 + r + ty) * NQKV + 2560 + g * 64 + tx];
  __syncthreads();
  #pragma unroll
  for (int r = 0; r < 64; r += 4)
    vT[((size_t)((bb * 8 + g) * 64) + r + ty) * SEQ + s0 + tx] = t[tx][r + ty];
}

// ---------------- bf16 GEMM: C[M][ldc] = A[M][K] * Bt[N][K]^T + bias ----------------
// m97 structure: 128x128 tile, BK=32, 4 waves, global_load_lds(16B), linear LDS.
template<int F32OUT>
__global__ __launch_bounds__(256, 3)
void k_gemm(const u16* __restrict__ A, const u16* __restrict__ Bt,
            const float* __restrict__ bias, void* __restrict__ Cv,
            int K, int ldc)
{
  __shared__ __align__(16) u16 lA[128 * 32];
  __shared__ __align__(16) u16 lB[128 * 32];
  const int tid = threadIdx.x;
  const int lane = tid & 63, wid = tid >> 6;
  const int fr = lane & 15, fq = lane >> 4;
  const int n0 = blockIdx.x * 128, m0 = blockIdx.y * 128;
  const int wr = wid >> 1, wc = wid & 1;    // wave's 64x64 output sub-tile

  f32x4 acc[4][4];
  #pragma unroll
  for (int i = 0; i < 4; ++i)
    #pragma unroll
    for (int j = 0; j < 4; ++j) acc[i][j] = f32x4{0.f, 0.f, 0.f, 0.f};

  const int s0 = (wid * 2 + 0) * 64 + lane;
  const int s1 = (wid * 2 + 1) * 64 + lane;
  const int r0 = s0 >> 2, k0s = 8 * (s0 & 3);
  const int r1 = s1 >> 2, k1s = 8 * (s1 & 3);
  const u16* gA0 = A  + (size_t)(m0 + r0) * K + k0s;
  const u16* gA1 = A  + (size_t)(m0 + r1) * K + k1s;
  const u16* gB0 = Bt + (size_t)(n0 + r0) * K + k0s;
  const u16* gB1 = Bt + (size_t)(n0 + r1) * K + k1s;
  u16* lA0 = &lA[(wid * 2 + 0) * 512];
  u16* lA1 = &lA[(wid * 2 + 1) * 512];
  u16* lB0 = &lB[(wid * 2 + 0) * 512];
  u16* lB1 = &lB[(wid * 2 + 1) * 512];

  int aoff[4], boff[4];                     // linear ds_read byte offsets
  #pragma unroll
  for (int i = 0; i < 4; ++i) {
    aoff[i] = (wr * 64 + i * 16 + fr) * 64 + fq * 16;
    boff[i] = (wc * 64 + i * 16 + fr) * 64 + fq * 16;
  }
  const char* laB = (const char*)lA;
  const char* lbB = (const char*)lB;

  for (int kt = 0; kt < K; kt += 32) {
    gld16(gA0, lA0); gld16(gA1, lA1);
    gld16(gB0, lB0); gld16(gB1, lB1);
    gA0 += 32; gA1 += 32; gB0 += 32; gB1 += 32;
    __syncthreads();                         // drains vmcnt -> tiles visible
    bf16x8 a[4], b[4];
    #pragma unroll
    for (int i = 0; i < 4; ++i) a[i] = *(const bf16x8*)(laB + aoff[i]);
    #pragma unroll
    for (int j = 0; j < 4; ++j) b[j] = *(const bf16x8*)(lbB + boff[j]);
    #pragma unroll
    for (int i = 0; i < 4; ++i)
      #pragma unroll
      for (int j = 0; j < 4; ++j)
        acc[i][j] = mfma16(a[i], b[j], acc[i][j]);
    __syncthreads();                         // before next overwrite
  }

  // epilogue: C/D layout col = lane&15, row = (lane>>4)*4 + t  [verified m89/m91]
  #pragma unroll
  for (int i = 0; i < 4; ++i) {
    const int row = m0 + wr * 64 + i * 16 + fq * 4;
    #pragma unroll
    for (int j = 0; j < 4; ++j) {
      const int col = n0 + wc * 64 + j * 16 + fr;
      const float bvl = bias[col];
      #pragma unroll
      for (int t = 0; t < 4; ++t) {
        const float val = acc[i][j][t] + bvl;
        if (F32OUT)
          ((float*)Cv)[(size_t)(row + t) * ldc + col] = val;
        else
          ((u16*)Cv)[(size_t)(row + t) * ldc + col] = f2bf(val);
      }
    }
  }
}

// ---------------- MFMA flash attention: swapped-QK^T, in-register softmax ----------------
// 1 wave = 32 q-rows of one (b,h); KV tile = 32. S^T = mfma32(K, Q) puts a full
// 32-key slice of ONE q-row in each lane (col=q=lane&31, key=(reg&3)+8*(reg>>2)+4*hi).
// Softmax: in-lane tree + 1 shfl. P -> bf16 via cvt_pk, redistributed to the PV
// B-frag with 4 half-swap shuffles. PV: O^T[d][q] = mfma32(V^T, P). No LDS, no barriers.
__global__ __launch_bounds__(64, 3)
void k_attn(const u16* __restrict__ qkv, const u16* __restrict__ vT,
            u16* __restrict__ ctx)
{
  const int lane = threadIdx.x & 63;
  const int q = lane & 31, hi = lane >> 5;
  const int h = blockIdx.y, bb = blockIdx.z, g = h >> 2;   // GS = 4
  const int qrow = blockIdx.x * 32 + q;
  const size_t tokbase = (size_t)bb * SEQ;

  // Q B-frag: Q[qrow][d = 16c + 8hi + e]
  bf16x8 aq[4];
  {
    const u16* qp = qkv + (tokbase + qrow) * NQKV + h * 64 + hi * 8;
    #pragma unroll
    for (int c = 0; c < 4; ++c) aq[c] = *(const bf16x8*)(qp + 16 * c);
  }
  f32x16 o0, o1;                              // O^T[d][q]: d-half 0/1
  #pragma unroll
  for (int r = 0; r < 16; ++r) { o0[r] = 0.f; o1[r] = 0.f; }
  float m = -3e38f, l = 0.f;

  const u16* kbase  = qkv + tokbase * NQKV + 2048 + g * 64 + hi * 8;  // + (tk+q)*NQKV + 16c
  const u16* v0base = vT + ((size_t)(bb * 8 + g) * 64 + q) * SEQ + hi * 8;
  const u16* v1base = v0base + (size_t)32 * SEQ;

  const float cs  = 0.18033688011112042f;     // log2(e)/sqrt(64)
  const float thr = 44.3614195558365f;        // 8/cs: P bounded by 2^8

  // preload K tile 0: A-frag K[key = tk + (l&31)][d = 16c + 8hi + e]
  bf16x8 kf[4];
  {
    const u16* kr = kbase + (size_t)q * NQKV;
    #pragma unroll
    for (int c = 0; c < 4; ++c) kf[c] = *(const bf16x8*)(kr + 16 * c);
  }

  for (int tk = 0; tk < SEQ; tk += 32) {
    // V A-frags for this tile (in flight across QK + softmax): V^T[d][key]
    bf16x8 vf0a = *(const bf16x8*)(v0base + tk);        // d 0-31,  keys tk+0..15
    bf16x8 vf1a = *(const bf16x8*)(v1base + tk);        // d 32-63, keys tk+0..15
    bf16x8 vf0b = *(const bf16x8*)(v0base + tk + 16);   // d 0-31,  keys tk+16..31
    bf16x8 vf1b = *(const bf16x8*)(v1base + tk + 16);

    // S^T[key][q] = K . Q
    f32x16 s;
    #pragma unroll
    for (int r = 0; r < 16; ++r) s[r] = 0.f;
    __builtin_amdgcn_s_setprio(1);
    #pragma unroll
    for (int c = 0; c < 4; ++c) s = mfma32(kf[c], aq[c], s);
    __builtin_amdgcn_s_setprio(0);

    // prefetch next K tile (in flight across softmax + PV)
    {
      const int tn = (tk + 32 < SEQ) ? tk + 32 : 0;
      const u16* kr = kbase + (size_t)(tn + q) * NQKV;
      #pragma unroll
      for (int c = 0; c < 4; ++c) kf[c] = *(const bf16x8*)(kr + 16 * c);
    }

    // row max: in-lane tree over 16 regs, then cross hi-half
    float t8[8];
    #pragma unroll
    for (int r = 0; r < 8; ++r) t8[r] = fmaxf(s[r], s[r + 8]);
    float t4a = fmaxf(t8[0], t8[4]), t4b = fmaxf(t8[1], t8[5]);
    float t4c = fmaxf(t8[2], t8[6]), t4d = fmaxf(t8[3], t8[7]);
    float mx = fmaxf(fmaxf(t4a, t4b), fmaxf(t4c, t4d));
    mx = fmaxf(mx, __shfl_xor(mx, 32));

    if (!__all(mx - m <= thr)) {              // T13 defer-max
      const float mn = fmaxf(m, mx);
      const float rs = exp2f((m - mn) * cs);
      m = mn; l *= rs;
      #pragma unroll
      for (int r = 0; r < 16; ++r) { o0[r] *= rs; o1[r] *= rs; }
    }

    const float mb = m * cs;                  // fold: exp2(s*cs - m*cs)
    float p[16];
    #pragma unroll
    for (int r = 0; r < 16; ++r) p[r] = exp2f(s[r] * cs - mb);
    float a8[8];
    #pragma unroll
    for (int r = 0; r < 8; ++r) a8[r] = p[r] + p[r + 8];
    float sum = ((a8[0] + a8[4]) + (a8[1] + a8[5])) + ((a8[2] + a8[6]) + (a8[3] + a8[7]));
    sum += __shfl_xor(sum, 32);
    l += sum;

    // P -> bf16 words; word u covers keys (8*(u>>1) + 4hi + 2*(u&1), +1)
    u32 w0 = cvtpk(p[0],  p[1]),  w1 = cvtpk(p[2],  p[3]);
    u32 w2 = cvtpk(p[4],  p[5]),  w3 = cvtpk(p[6],  p[7]);
    u32 w4 = cvtpk(p[8],  p[9]),  w5 = cvtpk(p[10], p[11]);
    u32 w6 = cvtpk(p[12], p[13]), w7 = cvtpk(p[14], p[15]);

    // half-swap exchange -> PV B-frag words (emulated permlane32_swap):
    // pair (wa,wb): out0 = [wa.lo | wb.lo], out1 = [wa.hi | wb.hi]
    u32 cA = __shfl_xor(hi ? w0 : w2, 32);
    u32 cB = __shfl_xor(hi ? w1 : w3, 32);
    u32 cC = __shfl_xor(hi ? w4 : w6, 32);
    u32 cD = __shfl_xor(hi ? w5 : w7, 32);
    u32x4 t0, t1;
    t0.x = hi ? cA : w0;  t0.y = hi ? cB : w1;   // kc0: keys 0-7 (hi=0) / 8-15 (hi=1)
    t0.z = hi ? w2 : cA;  t0.w = hi ? w3 : cB;
    t1.x = hi ? cC : w4;  t1.y = hi ? cD : w5;   // kc1: keys 16-23 / 24-31
    t1.z = hi ? w6 : cC;  t1.w = hi ? w7 : cD;
    bf16x8 pb0 = __builtin_bit_cast(bf16x8, t0);
    bf16x8 pb1 = __builtin_bit_cast(bf16x8, t1);

    // O^T[d][q] += V^T[d][k] . P[q][k]
    __builtin_amdgcn_s_setprio(1);
    o0 = mfma32(vf0a, pb0, o0);
    o1 = mfma32(vf1a, pb0, o1);
    o0 = mfma32(vf0b, pb1, o0);
    o1 = mfma32(vf1b, pb1, o1);
    __builtin_amdgcn_s_setprio(0);
  }

  // store: lane holds O^T[d][qrow]; reg 4t+e -> d = 8t + 4hi + e (contiguous quads)
  const float inv = 1.0f / l;
  u16* cp = ctx + (tokbase + qrow) * DMODEL + h * 64;
  #pragma unroll
  for (int t = 0; t < 4; ++t) {
    ushort4 oa, ob;
    oa.x = f2bf(o0[4*t+0] * inv); oa.y = f2bf(o0[4*t+1] * inv);
    oa.z = f2bf(o0[4*t+2] * inv); oa.w = f2bf(o0[4*t+3] * inv);
    *reinterpret_cast<ushort4*>(cp + 8*t + 4*hi) = oa;
    ob.x = f2bf(o1[4*t+0] * inv); ob.y = f2bf(o1[4*t+1] * inv);
    ob.z = f2bf(o1[4*t+2] * inv); ob.w = f2bf(o1[4*t+3] * inv);
    *reinterpret_cast<ushort4*>(cp + 32 + 8*t + 4*hi) = ob;
  }
}

extern "C" void kernel_launch(void* const* d_in, const int* in_sizes, int n_in,
                              void* d_out, int out_size, void* d_ws, size_t ws_size,
                              hipStream_t stream) {
  const float* x  = (const float*)d_in[0];
  const float* Wq = (const float*)d_in[1];
  const float* bq = (const float*)d_in[2];
  const float* Wk = (const float*)d_in[3];
  const float* bk = (const float*)d_in[4];
  const float* Wv = (const float*)d_in[5];
  const float* bv = (const float*)d_in[6];
  const float* Wo = (const float*)d_in[7];
  const float* bo = (const float*)d_in[8];

  char* ws = (char*)d_ws;
  size_t off = 0;
  auto take = [&](size_t bytes) { char* p = ws + off; off += (bytes + 255) & ~(size_t)255; return p; };
  u16*   xb    = (u16*)  take((size_t)MTOK * DMODEL * 2);   // x bf16; REUSED as ctx after gemm1
  u16*   wqkvT = (u16*)  take((size_t)NQKV * DMODEL * 2);   // [Wq;Wk;Wv] transposed
  u16*   woT   = (u16*)  take((size_t)DMODEL * DMODEL * 2); // Wo transposed
  u16*   qkv   = (u16*)  take((size_t)MTOK * NQKV * 2);     // projections (Q,K,V)
  u16*   vTb   = (u16*)  take((size_t)2 * NGRP * DHEAD * SEQ * 2); // V^T [b,g,d,s]
  float* bqkv  = (float*)take((size_t)NQKV * 4);            // packed qkv bias

  // ws overflow guard: if scratch too small, emit zeros (signature: absmax == max|ref|)
  if (off > ws_size) {
    hipMemsetAsync(d_out, 0, (size_t)out_size * 4, stream);
    return;
  }

  dim3 tb(32, 8);
  k_cvt<<<(MTOK * DMODEL) / (4 * 256), 256, 0, stream>>>(x, xb);
  k_tconv<<<dim3(64, 64), tb, 0, stream>>>(Wq, wqkvT, 2048);
  k_tconv<<<dim3(16, 64), tb, 0, stream>>>(Wk, wqkvT + (size_t)2048 * DMODEL, 512);
  k_tconv<<<dim3(16, 64), tb, 0, stream>>>(Wv, wqkvT + (size_t)2560 * DMODEL, 512);
  k_tconv<<<dim3(64, 64), tb, 0, stream>>>(Wo, woT, 2048);
  k_packbias<<<NQKV / 256, 256, 0, stream>>>(bq, bk, bv, bqkv);

  // QKV projection: M=4096, N=3072, K=2048 (bf16 out)
  k_gemm<0><<<dim3(NQKV / 128, MTOK / 128), 256, 0, stream>>>(
      xb, wqkvT, bqkv, qkv, DMODEL, NQKV);

  // V transpose for the PV step's A-operand
  k_vt<<<512, 256, 0, stream>>>(qkv, vTb);

  // MFMA flash attention: 1 wave per 32 q-rows; ctx into xb
  u16* ctxb = xb;
  k_attn<<<dim3(SEQ / 32, NHEAD, 2), 64, 0, stream>>>(qkv, vTb, ctxb);

  // output projection: M=4096, N=2048, K=2048 -> d_out (FLOAT32)
  k_gemm<1><<<dim3(DMODEL / 128, MTOK / 128), 256, 0, stream>>>(
      ctxb, woT, bo, d_out, DMODEL, DMODEL);
}

// Round 7
// 262.525 us; speedup vs baseline: 2.2602x; 1.4117x over previous
//
#include <hip/hip_runtime.h>
#include <stdint.h>

#define DEVINL __device__ __forceinline__

typedef unsigned short u16;
typedef unsigned int   u32;
typedef __attribute__((ext_vector_type(8)))  __bf16 bf16x8;
typedef __attribute__((ext_vector_type(4)))  float  f32x4;
typedef __attribute__((ext_vector_type(16))) float  f32x16;
typedef __attribute__((ext_vector_type(4)))  u32    u32x4;

static constexpr int SEQ    = 2048;
static constexpr int DMODEL = 2048;
static constexpr int NHEAD  = 32;
static constexpr int NGRP   = 8;
static constexpr int DHEAD  = 64;
static constexpr int MTOK   = 2 * SEQ;                       // 4096 tokens (B*S)
static constexpr int NQKV   = NHEAD*DHEAD + 2*NGRP*DHEAD;    // 3072

DEVINL u16 f2bf(float f) {                 // f32 -> bf16 RNE
  unsigned u = __builtin_bit_cast(unsigned, f);
  u += 0x7fffu + ((u >> 16) & 1u);
  return (u16)(u >> 16);
}

DEVINL void gld16(const void* g, void* l) {   // global -> LDS direct, 16B/lane
  typedef __attribute__((address_space(1))) const void* gp_t;
  typedef __attribute__((address_space(3))) void* lp_t;
  __builtin_amdgcn_global_load_lds((gp_t)g, (lp_t)l, 16, 0, 0);
}

DEVINL f32x4 mfma16(bf16x8 a, bf16x8 b, f32x4 c) {
  return __builtin_amdgcn_mfma_f32_16x16x32_bf16(a, b, c, 0, 0, 0);
}
DEVINL f32x16 mfma32(bf16x8 a, bf16x8 b, f32x16 c) {
  return __builtin_amdgcn_mfma_f32_32x32x16_bf16(a, b, c, 0, 0, 0);
}
DEVINL u32 cvtpk(float lo, float hi_) {        // bf16(lo) in low16, bf16(hi_) in high16
  u32 r;
  asm("v_cvt_pk_bf16_f32 %0, %1, %2" : "=v"(r) : "v"(lo), "v"(hi_));
  return r;
}

// ---------------- x: f32 -> bf16 (vectorized) ----------------
__global__ void k_cvt(const float* __restrict__ s, u16* __restrict__ d) {
  int i = (blockIdx.x * 256 + threadIdx.x) * 4;
  float4 v = *reinterpret_cast<const float4*>(s + i);
  ushort4 o;
  o.x = f2bf(v.x); o.y = f2bf(v.y); o.z = f2bf(v.z); o.w = f2bf(v.w);
  *reinterpret_cast<ushort4*>(d + i) = o;
}

// ---- weights: transpose + cast. dst[n][k] = src[k][n], dst leading dim = DMODEL ----
__global__ void k_tconv(const float* __restrict__ src, u16* __restrict__ dst, int N) {
  __shared__ float t[32][33];
  int n0 = blockIdx.x * 32, k0 = blockIdx.y * 32;
  int tx = threadIdx.x, ty = threadIdx.y;   // 32 x 8
  #pragma unroll
  for (int r = 0; r < 32; r += 8)
    t[r + ty][tx] = src[(size_t)(k0 + r + ty) * N + n0 + tx];
  __syncthreads();
  #pragma unroll
  for (int r = 0; r < 32; r += 8)
    dst[(size_t)(n0 + r + ty) * DMODEL + k0 + tx] = f2bf(t[tx][r + ty]);
}

__global__ void k_packbias(const float* __restrict__ bq, const float* __restrict__ bk,
                           const float* __restrict__ bv, float* __restrict__ d) {
  int i = blockIdx.x * 256 + threadIdx.x;   // 3072 threads
  d[i] = i < 2048 ? bq[i] : (i < 2560 ? bk[i - 2048] : bv[i - 2560]);
}

// ---- K/V fragment pre-pack: out[((bg*64 + st)*4 + frag)*64 + lane] = 16B the
// attention wave's `lane` consumes for `frag` of KV-tile `st`. Inner-loop loads
// become base + lane*16 (perfectly coalesced). Scatter paid once here via LDS.
// ISV=0: K A-frags  (row=key=lane&31, k-dim d = 16c + 8hi + e)
// ISV=1: V A-frags  (row=d=(j&1)*32 + (lane&31), k-dim key = (j>>1)*16 + hi*8 + e)
template<int ISV>
__global__ void k_pack(const u16* __restrict__ qkv, u16* __restrict__ out) {
  __shared__ u16 t[64][72];                 // [token_local][feat], 16B-aligned rows
  const int blk = blockIdx.x;               // bb*256 + g*32 + sblk  (2*8*32 = 512)
  const int sblk = blk & 31, g = (blk >> 5) & 7, bb = blk >> 8;
  const int tid = threadIdx.x;
  const size_t srcbase = ((size_t)bb * SEQ + sblk * 64) * NQKV + (ISV ? 2560 : 2048) + g * 64;
  // coalesced load: 64 tokens x 64 feats, 16B chunks
  #pragma unroll
  for (int i = 0; i < 2; ++i) {
    int c = tid * 2 + i;                    // 512 chunks of 8 u16
    int row = c >> 3, dc = (c & 7) * 8;
    *(bf16x8*)&t[row][dc] = *(const bf16x8*)(qkv + srcbase + (size_t)row * NQKV + dc);
  }
  __syncthreads();
  const int bg = bb * 8 + g;
  #pragma unroll
  for (int r = 0; r < 2; ++r) {
    int f = tid + 256 * r;                  // 512 frags: stl(2) x cj(4) x lane(64)
    int lane = f & 63, cj = (f >> 6) & 3, stl = f >> 8;
    int q = lane & 31, hi = lane >> 5;
    size_t o = ((((size_t)bg * 64 + sblk * 2 + stl) * 4 + cj) * 64 + lane) * 8;
    if (ISV) {
      int dcol = (cj & 1) * 32 + q;
      int s0 = stl * 32 + (cj >> 1) * 16 + hi * 8;
      u16 tmp[8];
      #pragma unroll
      for (int e = 0; e < 8; ++e) tmp[e] = t[s0 + e][dcol];
      *(ushort4*)(out + o)     = *(ushort4*)&tmp[0];
      *(ushort4*)(out + o + 4) = *(ushort4*)&tmp[4];
    } else {
      int srow = stl * 32 + q;
      int d0 = cj * 16 + hi * 8;
      *(bf16x8*)(out + o) = *(const bf16x8*)&t[srow][d0];
    }
  }
}

// ---------------- bf16 GEMM: C[M][ldc] = A[M][K] * Bt[N][K]^T + bias ----------------
// m97 structure: 128x128 tile, BK=32, 4 waves, global_load_lds(16B), linear LDS.
template<int F32OUT>
__global__ __launch_bounds__(256, 3)
void k_gemm(const u16* __restrict__ A, const u16* __restrict__ Bt,
            const float* __restrict__ bias, void* __restrict__ Cv,
            int K, int ldc)
{
  __shared__ __align__(16) u16 lA[128 * 32];
  __shared__ __align__(16) u16 lB[128 * 32];
  const int tid = threadIdx.x;
  const int lane = tid & 63, wid = tid >> 6;
  const int fr = lane & 15, fq = lane >> 4;
  const int n0 = blockIdx.x * 128, m0 = blockIdx.y * 128;
  const int wr = wid >> 1, wc = wid & 1;    // wave's 64x64 output sub-tile

  f32x4 acc[4][4];
  #pragma unroll
  for (int i = 0; i < 4; ++i)
    #pragma unroll
    for (int j = 0; j < 4; ++j) acc[i][j] = f32x4{0.f, 0.f, 0.f, 0.f};

  const int s0 = (wid * 2 + 0) * 64 + lane;
  const int s1 = (wid * 2 + 1) * 64 + lane;
  const int r0 = s0 >> 2, k0s = 8 * (s0 & 3);
  const int r1 = s1 >> 2, k1s = 8 * (s1 & 3);
  const u16* gA0 = A  + (size_t)(m0 + r0) * K + k0s;
  const u16* gA1 = A  + (size_t)(m0 + r1) * K + k1s;
  const u16* gB0 = Bt + (size_t)(n0 + r0) * K + k0s;
  const u16* gB1 = Bt + (size_t)(n0 + r1) * K + k1s;
  u16* lA0 = &lA[(wid * 2 + 0) * 512];
  u16* lA1 = &lA[(wid * 2 + 1) * 512];
  u16* lB0 = &lB[(wid * 2 + 0) * 512];
  u16* lB1 = &lB[(wid * 2 + 1) * 512];

  int aoff[4], boff[4];                     // linear ds_read byte offsets
  #pragma unroll
  for (int i = 0; i < 4; ++i) {
    aoff[i] = (wr * 64 + i * 16 + fr) * 64 + fq * 16;
    boff[i] = (wc * 64 + i * 16 + fr) * 64 + fq * 16;
  }
  const char* laB = (const char*)lA;
  const char* lbB = (const char*)lB;

  for (int kt = 0; kt < K; kt += 32) {
    gld16(gA0, lA0); gld16(gA1, lA1);
    gld16(gB0, lB0); gld16(gB1, lB1);
    gA0 += 32; gA1 += 32; gB0 += 32; gB1 += 32;
    __syncthreads();                         // drains vmcnt -> tiles visible
    bf16x8 a[4], b[4];
    #pragma unroll
    for (int i = 0; i < 4; ++i) a[i] = *(const bf16x8*)(laB + aoff[i]);
    #pragma unroll
    for (int j = 0; j < 4; ++j) b[j] = *(const bf16x8*)(lbB + boff[j]);
    #pragma unroll
    for (int i = 0; i < 4; ++i)
      #pragma unroll
      for (int j = 0; j < 4; ++j)
        acc[i][j] = mfma16(a[i], b[j], acc[i][j]);
    __syncthreads();                         // before next overwrite
  }

  // epilogue: C/D layout col = lane&15, row = (lane>>4)*4 + t  [verified m89/m91]
  #pragma unroll
  for (int i = 0; i < 4; ++i) {
    const int row = m0 + wr * 64 + i * 16 + fq * 4;
    #pragma unroll
    for (int j = 0; j < 4; ++j) {
      const int col = n0 + wc * 64 + j * 16 + fr;
      const float bvl = bias[col];
      #pragma unroll
      for (int t = 0; t < 4; ++t) {
        const float val = acc[i][j][t] + bvl;
        if (F32OUT)
          ((float*)Cv)[(size_t)(row + t) * ldc + col] = val;
        else
          ((u16*)Cv)[(size_t)(row + t) * ldc + col] = f2bf(val);
      }
    }
  }
}

// ---------------- MFMA flash attention: swapped-QK^T, in-register softmax ----------------
// 1 wave = 32 q-rows of one (b,h); KV tile = 32; 4 waves/block share one head's K/V
// (same lines -> L1 hits). All K/V loads are coalesced frag-order reads from kswz/vswz.
// Softmax in-lane + 1 shfl; P->bf16 via cvt_pk + 4 half-swap shuffles. No LDS/barriers.
__global__ __launch_bounds__(256, 4)
void k_attn(const u16* __restrict__ qkv, const u16* __restrict__ kswz,
            const u16* __restrict__ vswz, u16* __restrict__ ctx)
{
  const int tid = threadIdx.x, lane = tid & 63, wid = tid >> 6;
  const int q = lane & 31, hi = lane >> 5;
  const int h = blockIdx.y, bb = blockIdx.z, g = h >> 2;   // GS = 4
  const int qrow = blockIdx.x * 128 + wid * 32 + q;
  const size_t tokbase = (size_t)bb * SEQ;

  // Q B-frag: Q[qrow][d = 16c + 8hi + e]
  bf16x8 aq[4];
  {
    const u16* qp = qkv + (tokbase + qrow) * NQKV + h * 64 + hi * 8;
    #pragma unroll
    for (int c = 0; c < 4; ++c) aq[c] = *(const bf16x8*)(qp + 16 * c);
  }
  f32x16 o0, o1;                              // O^T[d][q]: d-half 0/1
  #pragma unroll
  for (int r = 0; r < 16; ++r) { o0[r] = 0.f; o1[r] = 0.f; }
  float m = -3e38f, l = 0.f;

  const int bg = bb * 8 + g;
  const u16* kb = kswz + (size_t)bg * 131072 + lane * 8;   // + (st*4 + c)*512
  const u16* vb = vswz + (size_t)bg * 131072 + lane * 8;

  const float cs  = 0.18033688011112042f;     // log2(e)/sqrt(64)
  const float thr = 44.3614195558365f;        // 8/cs: P bounded by 2^8

  // preload K tile 0
  bf16x8 kf[4];
  #pragma unroll
  for (int c = 0; c < 4; ++c) kf[c] = *(const bf16x8*)(kb + c * 512);

  for (int st = 0; st < SEQ / 32; ++st) {
    // V A-frags for this tile (coalesced; in flight across QK + softmax)
    bf16x8 vf[4];
    #pragma unroll
    for (int j = 0; j < 4; ++j) vf[j] = *(const bf16x8*)(vb + (st * 4 + j) * 512);

    // S^T[key][q] = K . Q
    f32x16 s;
    #pragma unroll
    for (int r = 0; r < 16; ++r) s[r] = 0.f;
    __builtin_amdgcn_s_setprio(1);
    #pragma unroll
    for (int c = 0; c < 4; ++c) s = mfma32(kf[c], aq[c], s);
    __builtin_amdgcn_s_setprio(0);

    // prefetch next K tile (in flight across softmax + PV)
    {
      const int sn = (st + 1 < SEQ / 32) ? st + 1 : 0;
      #pragma unroll
      for (int c = 0; c < 4; ++c) kf[c] = *(const bf16x8*)(kb + (sn * 4 + c) * 512);
    }

    // row max: in-lane tree over 16 regs, then cross hi-half
    float t8[8];
    #pragma unroll
    for (int r = 0; r < 8; ++r) t8[r] = fmaxf(s[r], s[r + 8]);
    float t4a = fmaxf(t8[0], t8[4]), t4b = fmaxf(t8[1], t8[5]);
    float t4c = fmaxf(t8[2], t8[6]), t4d = fmaxf(t8[3], t8[7]);
    float mx = fmaxf(fmaxf(t4a, t4b), fmaxf(t4c, t4d));
    mx = fmaxf(mx, __shfl_xor(mx, 32));

    if (!__all(mx - m <= thr)) {              // T13 defer-max
      const float mn = fmaxf(m, mx);
      const float rs = exp2f((m - mn) * cs);
      m = mn; l *= rs;
      #pragma unroll
      for (int r = 0; r < 16; ++r) { o0[r] *= rs; o1[r] *= rs; }
    }

    const float mb = m * cs;                  // fold: exp2(s*cs - m*cs)
    float p[16];
    #pragma unroll
    for (int r = 0; r < 16; ++r) p[r] = exp2f(s[r] * cs - mb);
    float a8[8];
    #pragma unroll
    for (int r = 0; r < 8; ++r) a8[r] = p[r] + p[r + 8];
    float sum = ((a8[0] + a8[4]) + (a8[1] + a8[5])) + ((a8[2] + a8[6]) + (a8[3] + a8[7]));
    sum += __shfl_xor(sum, 32);
    l += sum;

    // P -> bf16 words; word u covers keys (8*(u>>1) + 4hi + 2*(u&1), +1)
    u32 w0 = cvtpk(p[0],  p[1]),  w1 = cvtpk(p[2],  p[3]);
    u32 w2 = cvtpk(p[4],  p[5]),  w3 = cvtpk(p[6],  p[7]);
    u32 w4 = cvtpk(p[8],  p[9]),  w5 = cvtpk(p[10], p[11]);
    u32 w6 = cvtpk(p[12], p[13]), w7 = cvtpk(p[14], p[15]);

    // half-swap exchange -> PV B-frag words (emulated permlane32_swap)
    u32 cA = __shfl_xor(hi ? w0 : w2, 32);
    u32 cB = __shfl_xor(hi ? w1 : w3, 32);
    u32 cC = __shfl_xor(hi ? w4 : w6, 32);
    u32 cD = __shfl_xor(hi ? w5 : w7, 32);
    u32x4 t0, t1;
    t0.x = hi ? cA : w0;  t0.y = hi ? cB : w1;   // keys 0-7 (hi=0) / 8-15 (hi=1)
    t0.z = hi ? w2 : cA;  t0.w = hi ? w3 : cB;
    t1.x = hi ? cC : w4;  t1.y = hi ? cD : w5;   // keys 16-23 / 24-31
    t1.z = hi ? w6 : cC;  t1.w = hi ? w7 : cD;
    bf16x8 pb0 = __builtin_bit_cast(bf16x8, t0);
    bf16x8 pb1 = __builtin_bit_cast(bf16x8, t1);

    // O^T[d][q] += V^T[d][k] . P[q][k]
    __builtin_amdgcn_s_setprio(1);
    o0 = mfma32(vf[0], pb0, o0);
    o1 = mfma32(vf[1], pb0, o1);
    o0 = mfma32(vf[2], pb1, o0);
    o1 = mfma32(vf[3], pb1, o1);
    __builtin_amdgcn_s_setprio(0);
  }

  // store: lane holds O^T[d][qrow]; reg 4t+e -> d = 8t + 4hi + e (contiguous quads)
  const float inv = 1.0f / l;
  u16* cp = ctx + (tokbase + qrow) * DMODEL + h * 64;
  #pragma unroll
  for (int t = 0; t < 4; ++t) {
    ushort4 oa, ob;
    oa.x = f2bf(o0[4*t+0] * inv); oa.y = f2bf(o0[4*t+1] * inv);
    oa.z = f2bf(o0[4*t+2] * inv); oa.w = f2bf(o0[4*t+3] * inv);
    *reinterpret_cast<ushort4*>(cp + 8*t + 4*hi) = oa;
    ob.x = f2bf(o1[4*t+0] * inv); ob.y = f2bf(o1[4*t+1] * inv);
    ob.z = f2bf(o1[4*t+2] * inv); ob.w = f2bf(o1[4*t+3] * inv);
    *reinterpret_cast<ushort4*>(cp + 32 + 8*t + 4*hi) = ob;
  }
}

extern "C" void kernel_launch(void* const* d_in, const int* in_sizes, int n_in,
                              void* d_out, int out_size, void* d_ws, size_t ws_size,
                              hipStream_t stream) {
  const float* x  = (const float*)d_in[0];
  const float* Wq = (const float*)d_in[1];
  const float* bq = (const float*)d_in[2];
  const float* Wk = (const float*)d_in[3];
  const float* bk = (const float*)d_in[4];
  const float* Wv = (const float*)d_in[5];
  const float* bv = (const float*)d_in[6];
  const float* Wo = (const float*)d_in[7];
  const float* bo = (const float*)d_in[8];

  char* ws = (char*)d_ws;
  size_t off = 0;
  auto take = [&](size_t bytes) { char* p = ws + off; off += (bytes + 255) & ~(size_t)255; return p; };
  u16*   xb    = (u16*)  take((size_t)MTOK * DMODEL * 2);   // x bf16; REUSED as ctx after gemm1
  u16*   wqkvT = (u16*)  take((size_t)NQKV * DMODEL * 2);   // [Wq;Wk;Wv] transposed
  u16*   woT   = (u16*)  take((size_t)DMODEL * DMODEL * 2); // Wo transposed
  u16*   qkv   = (u16*)  take((size_t)MTOK * NQKV * 2);     // projections (Q,K,V)
  u16*   kswz  = (u16*)  take((size_t)16 * 131072 * 2);     // K frag-packed, 4MB
  u16*   vswz  = (u16*)  take((size_t)16 * 131072 * 2);     // V frag-packed, 4MB
  float* bqkv  = (float*)take((size_t)NQKV * 4);            // packed qkv bias

  // ws overflow guard: if scratch too small, emit zeros (signature: absmax == max|ref|)
  if (off > ws_size) {
    hipMemsetAsync(d_out, 0, (size_t)out_size * 4, stream);
    return;
  }

  dim3 tb(32, 8);
  k_cvt<<<(MTOK * DMODEL) / (4 * 256), 256, 0, stream>>>(x, xb);
  k_tconv<<<dim3(64, 64), tb, 0, stream>>>(Wq, wqkvT, 2048);
  k_tconv<<<dim3(16, 64), tb, 0, stream>>>(Wk, wqkvT + (size_t)2048 * DMODEL, 512);
  k_tconv<<<dim3(16, 64), tb, 0, stream>>>(Wv, wqkvT + (size_t)2560 * DMODEL, 512);
  k_tconv<<<dim3(64, 64), tb, 0, stream>>>(Wo, woT, 2048);
  k_packbias<<<NQKV / 256, 256, 0, stream>>>(bq, bk, bv, bqkv);

  // QKV projection: M=4096, N=3072, K=2048 (bf16 out)
  k_gemm<0><<<dim3(NQKV / 128, MTOK / 128), 256, 0, stream>>>(
      xb, wqkvT, bqkv, qkv, DMODEL, NQKV);

  // K/V fragment pre-pack (coalesces all attention inner-loop loads)
  k_pack<0><<<512, 256, 0, stream>>>(qkv, kswz);
  k_pack<1><<<512, 256, 0, stream>>>(qkv, vswz);

  // MFMA flash attention: 4 waves/block share a head; ctx into xb
  u16* ctxb = xb;
  k_attn<<<dim3(SEQ / 128, NHEAD, 2), 256, 0, stream>>>(qkv, kswz, vswz, ctxb);

  // output projection: M=4096, N=2048, K=2048 -> d_out (FLOAT32)
  k_gemm<1><<<dim3(DMODEL / 128, MTOK / 128), 256, 0, stream>>>(
      ctxb, woT, bo, d_out, DMODEL, DMODEL);
}